// Round 1
// baseline (480.430 us; speedup 1.0000x reference)
//
#include <hip/hip_runtime.h>

typedef __attribute__((ext_vector_type(4))) float f32x4;
typedef __attribute__((ext_vector_type(8))) short short8;
typedef __attribute__((ext_vector_type(4))) float float4v;

// fp32 -> bf16 round-to-nearest-even (bit trick, matches hardware cvt for normals)
static __device__ __forceinline__ short f2bf(float x) {
  unsigned u = __builtin_bit_cast(unsigned, x);
  u = (u + 0x7FFFu + ((u >> 16) & 1u)) >> 16;
  return (short)u;
}

static __device__ __forceinline__ f32x4 mfma16x16x32(short8 a, short8 b, f32x4 c) {
  return __builtin_amdgcn_mfma_f32_16x16x32_bf16(a, b, c, 0, 0, 0);
}

// ---------------- fp32 -> bf16 elementwise convert ----------------
__global__ __launch_bounds__(256) void k_cvt(const float* __restrict__ in,
                                             short* __restrict__ out, int n) {
  int i = (blockIdx.x * 256 + threadIdx.x) * 8;
  if (i >= n) return;
  float4v a = *(const float4v*)(in + i);
  float4v b = *(const float4v*)(in + i + 4);
  short8 r;
  r[0] = f2bf(a[0]); r[1] = f2bf(a[1]); r[2] = f2bf(a[2]); r[3] = f2bf(a[3]);
  r[4] = f2bf(b[0]); r[5] = f2bf(b[1]); r[6] = f2bf(b[2]); r[7] = f2bf(b[3]);
  *(short8*)(out + i) = r;
}

// ---------------- fp32 W (K x N) -> bf16 W^T (N x K), tiled ----------------
__global__ __launch_bounds__(256) void k_transpose(const float* __restrict__ W0, const float* __restrict__ W1,
                                                   const float* __restrict__ W2, const float* __restrict__ W3,
                                                   short* __restrict__ T0, short* __restrict__ T1,
                                                   short* __restrict__ T2, short* __restrict__ T3, int Dm) {
  const float* W = blockIdx.z == 0 ? W0 : blockIdx.z == 1 ? W1 : blockIdx.z == 2 ? W2 : W3;
  short*       T = blockIdx.z == 0 ? T0 : blockIdx.z == 1 ? T1 : blockIdx.z == 2 ? T2 : T3;
  __shared__ float tile[32][33];
  const int tx = threadIdx.x, ty = threadIdx.y;  // 32 x 8
  const int x0 = blockIdx.x * 32, y0 = blockIdx.y * 32;
#pragma unroll
  for (int i = 0; i < 4; i++)
    tile[ty + i * 8][tx] = W[(size_t)(y0 + ty + i * 8) * Dm + x0 + tx];
  __syncthreads();
#pragma unroll
  for (int i = 0; i < 4; i++)
    T[(size_t)(x0 + ty + i * 8) * Dm + y0 + tx] = f2bf(tile[tx][ty + i * 8]);
}

// ---------------- bf16 GEMM: C(MxN) = A(MxK) * Bt(NxK)^T ----------------
// 128x128 tile, BK=32, 4 waves (2x2), each wave 64x64 via 4x4 frags of 16x16x32 MFMA.
template <bool BF16_OUT>
__global__ __launch_bounds__(256) void k_gemm(const short* __restrict__ A, const short* __restrict__ Bt,
                                              void* __restrict__ Cv, int M, int N, int K) {
  constexpr int LDT = 40;  // padded LDS leading dim (bank-conflict break)
  __shared__ __align__(16) short As[128 * LDT];
  __shared__ __align__(16) short Bs[128 * LDT];
  const int t = threadIdx.x, lane = t & 63, wave = t >> 6;
  const int m0 = blockIdx.x * 128, n0 = blockIdx.y * 128;
  const int wr = wave >> 1, wc = wave & 1;
  f32x4 acc[4][4];
#pragma unroll
  for (int m = 0; m < 4; m++)
#pragma unroll
    for (int n = 0; n < 4; n++) acc[m][n] = (f32x4){0.f, 0.f, 0.f, 0.f};

  const int srow = t >> 1, scol = (t & 1) * 16;
  const short* pA = A + (size_t)(m0 + srow) * K + scol;
  const short* pB = Bt + (size_t)(n0 + srow) * K + scol;
  short* wA = As + srow * LDT + scol;
  short* wB = Bs + srow * LDT + scol;
  const int frow = lane & 15, fk = (lane >> 4) * 8;

  for (int k0 = 0; k0 < K; k0 += 32) {
    short8 a0 = *(const short8*)(pA + k0);
    short8 a1 = *(const short8*)(pA + k0 + 8);
    short8 b0 = *(const short8*)(pB + k0);
    short8 b1 = *(const short8*)(pB + k0 + 8);
    __syncthreads();
    *(short8*)(wA) = a0; *(short8*)(wA + 8) = a1;
    *(short8*)(wB) = b0; *(short8*)(wB + 8) = b1;
    __syncthreads();
    short8 af[4], bfr[4];
#pragma unroll
    for (int m = 0; m < 4; m++) af[m] = *(const short8*)(As + (wr * 64 + m * 16 + frow) * LDT + fk);
#pragma unroll
    for (int n = 0; n < 4; n++) bfr[n] = *(const short8*)(Bs + (wc * 64 + n * 16 + frow) * LDT + fk);
#pragma unroll
    for (int m = 0; m < 4; m++)
#pragma unroll
      for (int n = 0; n < 4; n++) acc[m][n] = mfma16x16x32(af[m], bfr[n], acc[m][n]);
  }

  const int crow = (lane >> 4) * 4, ccol = lane & 15;
#pragma unroll
  for (int m = 0; m < 4; m++)
#pragma unroll
    for (int n = 0; n < 4; n++) {
      const int gr = m0 + wr * 64 + m * 16 + crow;
      const int gc = n0 + wc * 64 + n * 16 + ccol;
#pragma unroll
      for (int r = 0; r < 4; r++) {
        if constexpr (BF16_OUT)
          ((short*)Cv)[(size_t)(gr + r) * N + gc] = f2bf(acc[m][n][r]);
        else
          ((float*)Cv)[(size_t)(gr + r) * N + gc] = acc[m][n][r];
      }
    }
}

// ---------------- flash attention (NO mask: reference mask is identically 0) ----------------
// Grid: (T/64, B*H). Block 256 = 4 waves; wave w owns q-rows [q0+16w, q0+16w+16).
// Online softmax in exp2 domain (scores pre-scaled by SCALE*log2(e) -> exact same softmax).
__global__ __launch_bounds__(256) void k_attn(const short* __restrict__ Q, const short* __restrict__ K,
                                              const short* __restrict__ V, short* __restrict__ O,
                                              int T, int Hn, float sl2e) {
  constexpr int KB = 64, HDc = 128;
  __shared__ __align__(16) short Ks[64][136];    // K-tile row-major, padded
  __shared__ __align__(16) short Vt[128][72];    // V-tile transposed: Vt[d][key], padded
  __shared__ __align__(16) short Ps[4][16][72];  // per-wave P tile, padded
  const int t = threadIdx.x, lane = t & 63, wave = t >> 6;
  const int b = blockIdx.y / Hn, h = blockIdx.y % Hn;
  const int q0 = blockIdx.x * 64;
  const int D = Hn * HDc;
  const short* Qp = Q + (size_t)b * T * D + h * HDc;
  const short* Kp = K + (size_t)b * T * D + h * HDc;
  const short* Vp = V + (size_t)b * T * D + h * HDc;

  short8 qf[4];
  {
    const int qr = q0 + wave * 16 + (lane & 15);
    const short* qrow = Qp + (size_t)qr * D + (lane >> 4) * 8;
#pragma unroll
    for (int dd = 0; dd < 4; dd++) qf[dd] = *(const short8*)(qrow + dd * 32);
  }
  f32x4 acc[8];
#pragma unroll
  for (int i = 0; i < 8; i++) acc[i] = (f32x4){0.f, 0.f, 0.f, 0.f};
  float mrow[4] = {-1e30f, -1e30f, -1e30f, -1e30f};
  float lrow[4] = {0.f, 0.f, 0.f, 0.f};

  for (int k0 = 0; k0 < T; k0 += KB) {
    __syncthreads();
    {  // stage K tile (64 x 128), vectorized
      const int r = t >> 2, c = (t & 3) * 32;
      const short* src = Kp + (size_t)(k0 + r) * D + c;
#pragma unroll
      for (int i = 0; i < 4; i++) *(short8*)(&Ks[r][c + i * 8]) = *(const short8*)(src + i * 8);
    }
    {  // stage V transposed: wave w covers d in [32w, 32w+32), lane = key
      const int key = lane, dbase = wave * 32;
      const short* src = Vp + (size_t)(k0 + key) * D + dbase;
#pragma unroll
      for (int i2 = 0; i2 < 4; i2++) {
        short8 v = *(const short8*)(src + i2 * 8);
#pragma unroll
        for (int j = 0; j < 8; j++) Vt[dbase + i2 * 8 + j][key] = v[j];
      }
    }
    __syncthreads();

    // S = Q K^T (scaled into exp2 domain)
    f32x4 s[4];
#pragma unroll
    for (int n = 0; n < 4; n++) {
      f32x4 z = (f32x4){0.f, 0.f, 0.f, 0.f};
      const short* kb = &Ks[n * 16 + (lane & 15)][(lane >> 4) * 8];
#pragma unroll
      for (int dd = 0; dd < 4; dd++) {
        short8 kf = *(const short8*)(kb + dd * 32);
        z = mfma16x16x32(qf[dd], kf, z);
      }
#pragma unroll
      for (int r = 0; r < 4; r++) s[n][r] = z[r] * sl2e;
    }

    // online softmax: row stats across the 16 lanes sharing each q-row
    float pm[4];
#pragma unroll
    for (int r = 0; r < 4; r++) pm[r] = fmaxf(fmaxf(s[0][r], s[1][r]), fmaxf(s[2][r], s[3][r]));
#pragma unroll
    for (int msk = 1; msk < 16; msk <<= 1)
#pragma unroll
      for (int r = 0; r < 4; r++) pm[r] = fmaxf(pm[r], __shfl_xor(pm[r], msk));
    float f[4], rs[4];
#pragma unroll
    for (int r = 0; r < 4; r++) {
      const float mn = fmaxf(mrow[r], pm[r]);
      f[r] = exp2f(mrow[r] - mn);
      mrow[r] = mn;
      rs[r] = 0.f;
    }
#pragma unroll
    for (int n = 0; n < 4; n++)
#pragma unroll
      for (int r = 0; r < 4; r++) {
        const float p = exp2f(s[n][r] - mrow[r]);
        s[n][r] = p;
        rs[r] += p;
      }
#pragma unroll
    for (int msk = 1; msk < 16; msk <<= 1)
#pragma unroll
      for (int r = 0; r < 4; r++) rs[r] += __shfl_xor(rs[r], msk);
#pragma unroll
    for (int r = 0; r < 4; r++) lrow[r] = lrow[r] * f[r] + rs[r];
#pragma unroll
    for (int i = 0; i < 8; i++)
#pragma unroll
      for (int r = 0; r < 4; r++) acc[i][r] *= f[r];

    // P -> per-wave LDS (bf16)
#pragma unroll
    for (int n = 0; n < 4; n++)
#pragma unroll
      for (int r = 0; r < 4; r++)
        Ps[wave][(lane >> 4) * 4 + r][n * 16 + (lane & 15)] = f2bf(s[n][r]);
    asm volatile("s_waitcnt lgkmcnt(0)" ::: "memory");

    // O += P V
#pragma unroll
    for (int kk = 0; kk < 2; kk++) {
      short8 pa = *(const short8*)(&Ps[wave][lane & 15][kk * 32 + (lane >> 4) * 8]);
#pragma unroll
      for (int n8 = 0; n8 < 8; n8++) {
        short8 vb = *(const short8*)(&Vt[n8 * 16 + (lane & 15)][kk * 32 + (lane >> 4) * 8]);
        acc[n8] = mfma16x16x32(pa, vb, acc[n8]);
      }
    }
  }

  const int crow = (lane >> 4) * 4, ccol = lane & 15;
#pragma unroll
  for (int n8 = 0; n8 < 8; n8++)
#pragma unroll
    for (int r = 0; r < 4; r++) {
      const int qr = q0 + wave * 16 + crow + r;
      const float v = acc[n8][r] / lrow[r];
      O[(size_t)(b * T + qr) * D + h * HDc + n8 * 16 + ccol] = f2bf(v);
    }
}

extern "C" void kernel_launch(void* const* d_in, const int* in_sizes, int n_in,
                              void* d_out, int out_size, void* d_ws, size_t ws_size,
                              hipStream_t stream) {
  const float* hs = (const float*)d_in[0];
  const float* Wq = (const float*)d_in[1];
  const float* Wk = (const float*)d_in[2];
  const float* Wv = (const float*)d_in[3];
  const float* Wo = (const float*)d_in[4];
  // d_in[5] (Wd), d_in[6] (bd): dead code — jnp.maximum(dms, causal) == 0 everywhere.
  float* out = (float*)d_out;

  const int B = 2, T = 2048, D = 2048, H = 16;
  const int M = B * T;
  const float sl2e = 0.1275174385f;  // (1/sqrt(128)) * log2(e)

  short* hsb = (short*)d_ws;                 // M*D bf16
  short* WqT = hsb + (size_t)M * D;          // D*D each
  short* WkT = WqT + (size_t)D * D;
  short* WvT = WkT + (size_t)D * D;
  short* WoT = WvT + (size_t)D * D;
  short* Qb  = WoT + (size_t)D * D;          // M*D each
  short* Kb  = Qb + (size_t)M * D;
  short* Vb  = Kb + (size_t)M * D;
  short* AOb = Vb + (size_t)M * D;

  k_cvt<<<(M * D) / 2048, 256, 0, stream>>>(hs, hsb, M * D);
  k_transpose<<<dim3(D / 32, D / 32, 4), dim3(32, 8), 0, stream>>>(Wq, Wk, Wv, Wo, WqT, WkT, WvT, WoT, D);
  k_gemm<true><<<dim3(M / 128, D / 128), 256, 0, stream>>>(hsb, WqT, (void*)Qb, M, D, D);
  k_gemm<true><<<dim3(M / 128, D / 128), 256, 0, stream>>>(hsb, WkT, (void*)Kb, M, D, D);
  k_gemm<true><<<dim3(M / 128, D / 128), 256, 0, stream>>>(hsb, WvT, (void*)Vb, M, D, D);
  k_attn<<<dim3(T / 64, B * H), 256, 0, stream>>>(Qb, Kb, Vb, AOb, T, H, sl2e);
  k_gemm<false><<<dim3(M / 128, D / 128), 256, 0, stream>>>(AOb, WoT, (void*)out, M, D, D);
}

// Round 2
// 472.352 us; speedup vs baseline: 1.0171x; 1.0171x over previous
//
#include <hip/hip_runtime.h>
#include <stdint.h>

typedef __attribute__((ext_vector_type(4))) float f32x4;
typedef __attribute__((ext_vector_type(8))) short short8;
typedef __attribute__((ext_vector_type(4))) float float4v;

#define GLOAD_LDS16(gsrc, ldst)                                                        \
  __builtin_amdgcn_global_load_lds((const __attribute__((address_space(1))) void*)(gsrc), \
                                   (__attribute__((address_space(3))) void*)(ldst), 16, 0, 0)

// fp32 -> bf16 round-to-nearest-even
static __device__ __forceinline__ short f2bf(float x) {
  unsigned u = __builtin_bit_cast(unsigned, x);
  u = (u + 0x7FFFu + ((u >> 16) & 1u)) >> 16;
  return (short)u;
}

static __device__ __forceinline__ f32x4 mfma16x16x32(short8 a, short8 b, f32x4 c) {
  return __builtin_amdgcn_mfma_f32_16x16x32_bf16(a, b, c, 0, 0, 0);
}

// ---------------- fp32 -> bf16 elementwise convert ----------------
__global__ __launch_bounds__(256) void k_cvt(const float* __restrict__ in,
                                             short* __restrict__ out, int n) {
  int i = (blockIdx.x * 256 + threadIdx.x) * 8;
  if (i >= n) return;
  float4v a = *(const float4v*)(in + i);
  float4v b = *(const float4v*)(in + i + 4);
  short8 r;
  r[0] = f2bf(a[0]); r[1] = f2bf(a[1]); r[2] = f2bf(a[2]); r[3] = f2bf(a[3]);
  r[4] = f2bf(b[0]); r[5] = f2bf(b[1]); r[6] = f2bf(b[2]); r[7] = f2bf(b[3]);
  *(short8*)(out + i) = r;
}

// ---------------- fp32 W (K x N) -> bf16 W^T (N x K), tiled ----------------
__global__ __launch_bounds__(256) void k_transpose(const float* __restrict__ W0, const float* __restrict__ W1,
                                                   const float* __restrict__ W2, const float* __restrict__ W3,
                                                   short* __restrict__ T0, short* __restrict__ T1,
                                                   short* __restrict__ T2, short* __restrict__ T3, int Dm) {
  const float* W = blockIdx.z == 0 ? W0 : blockIdx.z == 1 ? W1 : blockIdx.z == 2 ? W2 : W3;
  short*       T = blockIdx.z == 0 ? T0 : blockIdx.z == 1 ? T1 : blockIdx.z == 2 ? T2 : T3;
  __shared__ float tile[32][33];
  const int tx = threadIdx.x, ty = threadIdx.y;  // 32 x 8
  const int x0 = blockIdx.x * 32, y0 = blockIdx.y * 32;
#pragma unroll
  for (int i = 0; i < 4; i++)
    tile[ty + i * 8][tx] = W[(size_t)(y0 + ty + i * 8) * Dm + x0 + tx];
  __syncthreads();
#pragma unroll
  for (int i = 0; i < 4; i++)
    T[(size_t)(x0 + ty + i * 8) * Dm + y0 + tx] = f2bf(tile[tx][ty + i * 8]);
}

// ---------------- bf16 GEMM (m97 structure): C(MxN) = A(MxK) * Bt(NxK)^T ----------------
// 128x128 tile, BK=32, global_load_lds width-16 staging into linear LDS, 2-barrier K-loop.
template <bool BF16_OUT>
__global__ __launch_bounds__(256) void k_gemm(const short* __restrict__ A, const short* __restrict__ Bt,
                                              void* __restrict__ Cv, int M, int N, int K) {
  __shared__ __align__(16) short As[128 * 32];
  __shared__ __align__(16) short Bs[128 * 32];
  const int t = threadIdx.x, lane = t & 63, wave = t >> 6;
  const int m0 = blockIdx.x * 128, n0 = blockIdx.y * 128;
  const int wr = wave >> 1, wc = wave & 1;
  f32x4 acc[4][4];
#pragma unroll
  for (int m = 0; m < 4; m++)
#pragma unroll
    for (int n = 0; n < 4; n++) acc[m][n] = (f32x4){0.f, 0.f, 0.f, 0.f};

  const int frow = lane & 15, fk = (lane >> 4) * 8;
  // staging geometry: granule g (16B, 8 elems) at LDS byte g*16; row = g>>2, c8 = g&3
  const int g0 = wave * 128 + lane;  // it adds 64
  const int sr0 = g0 >> 2, sc0 = (g0 & 3) * 8;
  const int sr1 = (g0 + 64) >> 2, sc1 = ((g0 + 64) & 3) * 8;

  for (int k0 = 0; k0 < K; k0 += 32) {
    __syncthreads();  // previous tile's frag reads complete
    GLOAD_LDS16(A + (size_t)(m0 + sr0) * K + k0 + sc0, As + (wave * 128) * 8);
    GLOAD_LDS16(Bt + (size_t)(n0 + sr0) * K + k0 + sc0, Bs + (wave * 128) * 8);
    GLOAD_LDS16(A + (size_t)(m0 + sr1) * K + k0 + sc1, As + (wave * 128 + 64) * 8);
    GLOAD_LDS16(Bt + (size_t)(n0 + sr1) * K + k0 + sc1, Bs + (wave * 128 + 64) * 8);
    __syncthreads();  // compiler drains vmcnt before barrier -> tiles visible
    short8 af[4], bfr[4];
#pragma unroll
    for (int m = 0; m < 4; m++) af[m] = *(const short8*)(As + (wr * 64 + m * 16 + frow) * 32 + fk);
#pragma unroll
    for (int n = 0; n < 4; n++) bfr[n] = *(const short8*)(Bs + (wc * 64 + n * 16 + frow) * 32 + fk);
#pragma unroll
    for (int m = 0; m < 4; m++)
#pragma unroll
      for (int n = 0; n < 4; n++) acc[m][n] = mfma16x16x32(af[m], bfr[n], acc[m][n]);
  }

  const int crow = (lane >> 4) * 4, ccol = lane & 15;
#pragma unroll
  for (int m = 0; m < 4; m++)
#pragma unroll
    for (int n = 0; n < 4; n++) {
      const int gr = m0 + wr * 64 + m * 16 + crow;
      const int gc = n0 + wc * 64 + n * 16 + ccol;
#pragma unroll
      for (int r = 0; r < 4; r++) {
        if constexpr (BF16_OUT)
          ((short*)Cv)[(size_t)(gr + r) * N + gc] = f2bf(acc[m][n][r]);
        else
          ((float*)Cv)[(size_t)(gr + r) * N + gc] = acc[m][n][r];
      }
    }
}

// ---------------- flash attention (mask == 0 identically; full softmax) ----------------
// Grid: (T/128, B*H), block 256 = 4 waves; wave w owns q-rows [q0+32w, q0+32w+32).
// K: global_load_lds staged, XOR-swizzled (c8 ^= row&7, involution on both sides).
// V^T, P: XOR-swizzled LDS (pitch 128B). Row-sum l accumulated via MFMA(P, ones).
__global__ __launch_bounds__(256) void k_attn(const short* __restrict__ Q, const short* __restrict__ K,
                                              const short* __restrict__ V, short* __restrict__ O,
                                              int T, int Hn, float sl2e) {
  constexpr int HD = 128;
  __shared__ __align__(16) short Ks[64 * 128];   // [key][d], swizzled granules
  __shared__ __align__(16) short Vt[128 * 64];   // [d][key], swizzled granules
  __shared__ __align__(16) short Ps[4][32 * 64]; // per-wave [q][key], swizzled granules
  const int t = threadIdx.x, lane = t & 63, wave = t >> 6;
  const int b = blockIdx.y / Hn, h = blockIdx.y % Hn;
  const int q0 = blockIdx.x * 128;
  const int D = Hn * HD;
  const short* Qp = Q + (size_t)b * T * D + h * HD;
  const short* Kp = K + (size_t)b * T * D + h * HD;
  const short* Vp = V + (size_t)b * T * D + h * HD;
  const int l15 = lane & 15, l4 = lane >> 4;

  short8 qf[2][4];
#pragma unroll
  for (int rg = 0; rg < 2; rg++) {
    const int qr = q0 + wave * 32 + rg * 16 + l15;
    const short* qrow = Qp + (size_t)qr * D + l4 * 8;
#pragma unroll
    for (int dd = 0; dd < 4; dd++) qf[rg][dd] = *(const short8*)(qrow + dd * 32);
  }
  short8 ones;
#pragma unroll
  for (int j = 0; j < 8; j++) ones[j] = (short)0x3F80;  // bf16 1.0

  f32x4 acc[2][8], lacc[2];
#pragma unroll
  for (int rg = 0; rg < 2; rg++) {
    lacc[rg] = (f32x4){0.f, 0.f, 0.f, 0.f};
#pragma unroll
    for (int i = 0; i < 8; i++) acc[rg][i] = (f32x4){0.f, 0.f, 0.f, 0.f};
  }
  float mrow[2][4];
#pragma unroll
  for (int rg = 0; rg < 2; rg++)
#pragma unroll
    for (int r = 0; r < 4; r++) mrow[rg][r] = -1e30f;

  for (int k0 = 0; k0 < T; k0 += 64) {
    __syncthreads();  // previous tile's LDS reads complete
    // --- stage K tile via global_load_lds: linear dest, inverse-swizzled source ---
#pragma unroll
    for (int it = 0; it < 4; it++) {
      const int g = it * 256 + t;               // granule 0..1023 (16B each)
      const int row = g >> 4, c8p = g & 15;
      const int c8l = c8p ^ (row & 7);
      GLOAD_LDS16(Kp + (size_t)(k0 + row) * D + c8l * 8, Ks + (it * 256 + wave * 64) * 8);
    }
    // --- stage V transposed (scalar swizzled writes): wave w covers d in [32w,32w+32) ---
    {
      const int key = lane, dbase = wave * 32;
      const short* src = Vp + (size_t)(k0 + key) * D + dbase;
#pragma unroll
      for (int i2 = 0; i2 < 4; i2++) {
        short8 v = *(const short8*)(src + i2 * 8);
#pragma unroll
        for (int j = 0; j < 8; j++) {
          const int d = dbase + i2 * 8 + j;
          Vt[d * 64 + (((key >> 3) ^ (d & 7)) << 3) + (key & 7)] = v[j];
        }
      }
    }
    __syncthreads();  // vmcnt+lgkm drained -> K,V tiles visible

    // --- S = Q K^T (exp2 domain) ---
    f32x4 s[2][4];
#pragma unroll
    for (int n = 0; n < 4; n++) {
      const int krow = n * 16 + l15;
      short8 kf[4];
#pragma unroll
      for (int dd = 0; dd < 4; dd++) {
        const int c8p = (dd * 4 + l4) ^ (krow & 7);
        kf[dd] = *(const short8*)(Ks + krow * 128 + c8p * 8);
      }
#pragma unroll
      for (int rg = 0; rg < 2; rg++) {
        f32x4 z = (f32x4){0.f, 0.f, 0.f, 0.f};
#pragma unroll
        for (int dd = 0; dd < 4; dd++) z = mfma16x16x32(qf[rg][dd], kf[dd], z);
#pragma unroll
        for (int r = 0; r < 4; r++) s[rg][n][r] = z[r] * sl2e;
      }
    }

    // --- online softmax (max via 16-lane shuffle reduce; sum via MFMA later) ---
#pragma unroll
    for (int rg = 0; rg < 2; rg++) {
      float pm[4];
#pragma unroll
      for (int r = 0; r < 4; r++)
        pm[r] = fmaxf(fmaxf(s[rg][0][r], s[rg][1][r]), fmaxf(s[rg][2][r], s[rg][3][r]));
#pragma unroll
      for (int msk = 1; msk < 16; msk <<= 1)
#pragma unroll
        for (int r = 0; r < 4; r++) pm[r] = fmaxf(pm[r], __shfl_xor(pm[r], msk));
      float f[4];
#pragma unroll
      for (int r = 0; r < 4; r++) {
        const float mn = fmaxf(mrow[rg][r], pm[r]);
        f[r] = exp2f(mrow[rg][r] - mn);
        mrow[rg][r] = mn;
      }
#pragma unroll
      for (int r = 0; r < 4; r++) lacc[rg][r] *= f[r];
#pragma unroll
      for (int i = 0; i < 8; i++)
#pragma unroll
        for (int r = 0; r < 4; r++) acc[rg][i][r] *= f[r];
      // P -> LDS (bf16, swizzled)
#pragma unroll
      for (int n = 0; n < 4; n++)
#pragma unroll
        for (int r = 0; r < 4; r++) {
          const float p = exp2f(s[rg][n][r] - mrow[rg][r]);
          const int k = n * 16 + l15;
          const int row = rg * 16 + l4 * 4 + r;
          Ps[wave][row * 64 + (((k >> 3) ^ (row & 7)) << 3) + (k & 7)] = f2bf(p);
        }
    }
    asm volatile("s_waitcnt lgkmcnt(0)" ::: "memory");
    __builtin_amdgcn_sched_barrier(0);

    // --- O += P V ; l += P * ones ---
#pragma unroll
    for (int kk = 0; kk < 2; kk++) {
      short8 pa[2];
#pragma unroll
      for (int rg = 0; rg < 2; rg++) {
        const int row = rg * 16 + l15;
        const int c8p = (kk * 4 + l4) ^ (row & 7);
        pa[rg] = *(const short8*)(&Ps[wave][row * 64 + c8p * 8]);
        lacc[rg] = mfma16x16x32(pa[rg], ones, lacc[rg]);
      }
#pragma unroll
      for (int n8 = 0; n8 < 8; n8++) {
        const int vrow = n8 * 16 + l15;
        const int c8p = (kk * 4 + l4) ^ (vrow & 7);
        short8 vb = *(const short8*)(&Vt[vrow * 64 + c8p * 8]);
        acc[0][n8] = mfma16x16x32(pa[0], vb, acc[0][n8]);
        acc[1][n8] = mfma16x16x32(pa[1], vb, acc[1][n8]);
      }
    }
  }

#pragma unroll
  for (int rg = 0; rg < 2; rg++) {
    float rl[4];
#pragma unroll
    for (int r = 0; r < 4; r++) rl[r] = 1.0f / lacc[rg][r];
#pragma unroll
    for (int n8 = 0; n8 < 8; n8++)
#pragma unroll
      for (int r = 0; r < 4; r++) {
        const int qr = q0 + wave * 32 + rg * 16 + l4 * 4 + r;
        O[(size_t)(b * T + qr) * D + h * HD + n8 * 16 + l15] = f2bf(acc[rg][n8][r] * rl[r]);
      }
  }
}

extern "C" void kernel_launch(void* const* d_in, const int* in_sizes, int n_in,
                              void* d_out, int out_size, void* d_ws, size_t ws_size,
                              hipStream_t stream) {
  const float* hs = (const float*)d_in[0];
  const float* Wq = (const float*)d_in[1];
  const float* Wk = (const float*)d_in[2];
  const float* Wv = (const float*)d_in[3];
  const float* Wo = (const float*)d_in[4];
  // d_in[5] (Wd), d_in[6] (bd): dead code — jnp.maximum(dms, causal) == 0 everywhere.
  float* out = (float*)d_out;

  const int B = 2, T = 2048, D = 2048, H = 16;
  const int M = B * T;
  const float sl2e = 0.1275174385f;  // (1/sqrt(128)) * log2(e)

  short* hsb = (short*)d_ws;                 // M*D bf16
  short* WqT = hsb + (size_t)M * D;          // D*D each
  short* WkT = WqT + (size_t)D * D;
  short* WvT = WkT + (size_t)D * D;
  short* WoT = WvT + (size_t)D * D;
  short* Qb  = WoT + (size_t)D * D;          // M*D each
  short* Kb  = Qb + (size_t)M * D;
  short* Vb  = Kb + (size_t)M * D;
  short* AOb = Vb + (size_t)M * D;

  k_cvt<<<(M * D) / 2048, 256, 0, stream>>>(hs, hsb, M * D);
  k_transpose<<<dim3(D / 32, D / 32, 4), dim3(32, 8), 0, stream>>>(Wq, Wk, Wv, Wo, WqT, WkT, WvT, WoT, D);
  k_gemm<true><<<dim3(M / 128, D / 128), 256, 0, stream>>>(hsb, WqT, (void*)Qb, M, D, D);
  k_gemm<true><<<dim3(M / 128, D / 128), 256, 0, stream>>>(hsb, WkT, (void*)Kb, M, D, D);
  k_gemm<true><<<dim3(M / 128, D / 128), 256, 0, stream>>>(hsb, WvT, (void*)Vb, M, D, D);
  k_attn<<<dim3(T / 128, B * H), 256, 0, stream>>>(Qb, Kb, Vb, AOb, T, H, sl2e);
  k_gemm<false><<<dim3(M / 128, D / 128), 256, 0, stream>>>(AOb, WoT, (void*)out, M, D, D);
}